// Round 1
// baseline (1970.170 us; speedup 1.0000x reference)
//
#include <hip/hip_runtime.h>
#include <cstdint>
#include <cstddef>

// Fused GRU over T=60 steps. One block owns TILE_N=64 rows; h lives in LDS.
// chars: [B=16][T=60][S=2000][C=64] f32; W_ih/W_hh: [192][64]; b_*: [192].
// out: [B][S][H=64] f32.
//
// LDS (128 KiB exactly):
//   xh[k][row], k-major: k in [0,64) = x_t, k in [64,128) = h_t
//   wRZ[k][j][0..1] = (W_r[j][k'], W_z[j][k'])  where k' selects W_ih (k<64) or W_hh
//   wN [k][j]       = W_ihn[j][k] (k<64) or W_hhn[j][k-64]
// Thread (512/block): GEMM role = channels {j0,j0+1} x rows [r0,r0+4);
// per k: ds_read_b128(xh) + ds_read_b128(wRZ pair) + ds_read_b64(wN pair) -> 24 FMA.

namespace {

constexpr int T_STEPS  = 60;
constexpr int S_DIM    = 2000;
constexpr int C_DIM    = 64;
constexpr int H_DIM    = 64;
constexpr int N_ROWS   = 16 * S_DIM;   // 32000
constexpr int TILE_N   = 64;
constexpr int NTHREADS = 512;
constexpr int KDIM     = 128;

__global__ __launch_bounds__(NTHREADS)
void gru_fused(const float* __restrict__ chars,
               const float* __restrict__ W_ih,
               const float* __restrict__ W_hh,
               const float* __restrict__ b_ih,
               const float* __restrict__ b_hh,
               float* __restrict__ out)
{
    __shared__ float xh [KDIM][TILE_N];      // 32 KiB
    __shared__ float wRZ[KDIM][H_DIM][2];    // 64 KiB
    __shared__ float wN [KDIM][H_DIM];       // 32 KiB

    const int tid = threadIdx.x;
    const int n0  = blockIdx.x * TILE_N;

    // ---- one-time: pack weights k-major ----
    {
        const int j  = tid & 63;
        const int k0 = (tid >> 6) * 16;      // 8 groups x 16 k
        #pragma unroll
        for (int kk = 0; kk < 16; ++kk) {
            const int k = k0 + kk;
            float wr, wz, wn;
            if (k < 64) {
                wr = W_ih[ j              * C_DIM + k];
                wz = W_ih[(H_DIM   + j)   * C_DIM + k];
                wn = W_ih[(2*H_DIM + j)   * C_DIM + k];
            } else {
                wr = W_hh[ j              * H_DIM + (k - 64)];
                wz = W_hh[(H_DIM   + j)   * H_DIM + (k - 64)];
                wn = W_hh[(2*H_DIM + j)   * H_DIM + (k - 64)];
            }
            wRZ[k][j][0] = wr;
            wRZ[k][j][1] = wz;
            wN [k][j]    = wn;
        }
    }
    // ---- one-time: h := 0 ----
    for (int e = tid; e < 64 * TILE_N; e += NTHREADS)
        xh[64 + (e >> 6)][e & 63] = 0.0f;

    // ---- roles ----
    const int j0 = (tid >> 4) * 2;           // GEMM: channel pair 0,2,...,62
    const int r0 = (tid & 15) * 4;           // GEMM: row group 0..60
    const int srowA = tid >> 4;              // stage/out: rows srowA, srowA+32
    const int srowB = srowA + 32;
    const int sc0   = (tid & 15) * 4;        // stage/out: col group

    const unsigned nA = n0 + srowA;
    const unsigned nB = n0 + srowB;
    const unsigned bA = nA / S_DIM, sA = nA % S_DIM;
    const unsigned bB = nB / S_DIM, sB = nB % S_DIM;
    const size_t tstride = (size_t)S_DIM * C_DIM;  // 128000 floats
    const float* xptrA = chars + ((size_t)bA * T_STEPS * S_DIM + sA) * C_DIM + sc0;
    const float* xptrB = chars + ((size_t)bB * T_STEPS * S_DIM + sB) * C_DIM + sc0;

    const float br0 = b_ih[j0]        + b_hh[j0];
    const float br1 = b_ih[j0+1]      + b_hh[j0+1];
    const float bz0 = b_ih[64+j0]     + b_hh[64+j0];
    const float bz1 = b_ih[64+j0+1]   + b_hh[64+j0+1];
    const float bn0 = b_ih[128+j0];
    const float bn1 = b_ih[128+j0+1];
    const float bh0 = b_hh[128+j0];
    const float bh1 = b_hh[128+j0+1];

    const float* xh_base  = &xh[0][r0];
    const float* wrz_base = &wRZ[0][j0][0];
    const float* wn_base  = &wN[0][j0];
    float* hrow0 = &xh[64 + j0    ][r0];
    float* hrow1 = &xh[64 + j0 + 1][r0];

    // prefetch x_0
    float4 xvA = *(const float4*)(xptrA);
    float4 xvB = *(const float4*)(xptrB);

    for (int t = 0; t < T_STEPS; ++t) {
        // publish x_t into LDS
        xh[sc0+0][srowA] = xvA.x; xh[sc0+1][srowA] = xvA.y;
        xh[sc0+2][srowA] = xvA.z; xh[sc0+3][srowA] = xvA.w;
        xh[sc0+0][srowB] = xvB.x; xh[sc0+1][srowB] = xvB.y;
        xh[sc0+2][srowB] = xvB.z; xh[sc0+3][srowB] = xvB.w;
        __syncthreads();

        // prefetch x_{t+1}; HBM latency hides under the GEMM below
        if (t + 1 < T_STEPS) {
            xvA = *(const float4*)(xptrA + (size_t)(t + 1) * tstride);
            xvB = *(const float4*)(xptrB + (size_t)(t + 1) * tstride);
        }

        float aR0[4], aR1[4], aZ0[4], aZ1[4], aN0[4], aN1[4], aH0[4], aH1[4];
        #pragma unroll
        for (int i = 0; i < 4; ++i) {
            aR0[i] = br0; aR1[i] = br1; aZ0[i] = bz0; aZ1[i] = bz1;
            aN0[i] = bn0; aN1[i] = bn1; aH0[i] = bh0; aH1[i] = bh1;
        }

        // k in [0,64): x-part feeds r, z, i_n
        #pragma unroll 8
        for (int k = 0; k < 64; ++k) {
            const float4 x4  = *(const float4*)(xh_base  + k * TILE_N);
            const float4 w4  = *(const float4*)(wrz_base + k * (H_DIM * 2));
            const float2 wn2 = *(const float2*)(wn_base  + k * H_DIM);
            const float xs[4] = {x4.x, x4.y, x4.z, x4.w};
            #pragma unroll
            for (int i = 0; i < 4; ++i) {
                aR0[i] = fmaf(xs[i], w4.x,  aR0[i]);
                aZ0[i] = fmaf(xs[i], w4.y,  aZ0[i]);
                aR1[i] = fmaf(xs[i], w4.z,  aR1[i]);
                aZ1[i] = fmaf(xs[i], w4.w,  aZ1[i]);
                aN0[i] = fmaf(xs[i], wn2.x, aN0[i]);
                aN1[i] = fmaf(xs[i], wn2.y, aN1[i]);
            }
        }
        // k in [64,128): h-part feeds r, z, h_n
        #pragma unroll 8
        for (int k = 64; k < 128; ++k) {
            const float4 x4  = *(const float4*)(xh_base  + k * TILE_N);
            const float4 w4  = *(const float4*)(wrz_base + k * (H_DIM * 2));
            const float2 wn2 = *(const float2*)(wn_base  + k * H_DIM);
            const float xs[4] = {x4.x, x4.y, x4.z, x4.w};
            #pragma unroll
            for (int i = 0; i < 4; ++i) {
                aR0[i] = fmaf(xs[i], w4.x,  aR0[i]);
                aZ0[i] = fmaf(xs[i], w4.y,  aZ0[i]);
                aR1[i] = fmaf(xs[i], w4.z,  aR1[i]);
                aZ1[i] = fmaf(xs[i], w4.w,  aZ1[i]);
                aH0[i] = fmaf(xs[i], wn2.x, aH0[i]);
                aH1[i] = fmaf(xs[i], wn2.y, aH1[i]);
            }
        }

        // gates + state update (thread-local: owns j0,j0+1 across its 4 rows)
        const float4 h4_0 = *(const float4*)hrow0;
        const float4 h4_1 = *(const float4*)hrow1;
        const float ho0[4] = {h4_0.x, h4_0.y, h4_0.z, h4_0.w};
        const float ho1[4] = {h4_1.x, h4_1.y, h4_1.z, h4_1.w};
        float hn0[4], hn1[4];
        #pragma unroll
        for (int i = 0; i < 4; ++i) {
            const float rg0 = 1.0f / (1.0f + expf(-aR0[i]));
            const float zg0 = 1.0f / (1.0f + expf(-aZ0[i]));
            const float th0 = tanhf(fmaf(rg0, aH0[i], aN0[i]));
            hn0[i] = fmaf(zg0, ho0[i] - th0, th0);   // (1-z)*n + z*h

            const float rg1 = 1.0f / (1.0f + expf(-aR1[i]));
            const float zg1 = 1.0f / (1.0f + expf(-aZ1[i]));
            const float th1 = tanhf(fmaf(rg1, aH1[i], aN1[i]));
            hn1[i] = fmaf(zg1, ho1[i] - th1, th1);
        }
        __syncthreads();   // all GEMM/hold reads of xh done
        *(float4*)hrow0 = make_float4(hn0[0], hn0[1], hn0[2], hn0[3]);
        *(float4*)hrow1 = make_float4(hn1[0], hn1[1], hn1[2], hn1[3]);
        // next iteration's x-publish touches only k<64; h writes touch k>=64;
        // next sync1 orders both against the next GEMM.
    }
    __syncthreads();

    // write h_final, coalesced via staging roles
    float4 oA, oB;
    oA.x = xh[64+sc0+0][srowA]; oA.y = xh[64+sc0+1][srowA];
    oA.z = xh[64+sc0+2][srowA]; oA.w = xh[64+sc0+3][srowA];
    oB.x = xh[64+sc0+0][srowB]; oB.y = xh[64+sc0+1][srowB];
    oB.z = xh[64+sc0+2][srowB]; oB.w = xh[64+sc0+3][srowB];
    *(float4*)(out + (size_t)nA * H_DIM + sc0) = oA;
    *(float4*)(out + (size_t)nB * H_DIM + sc0) = oB;
}

} // namespace

extern "C" void kernel_launch(void* const* d_in, const int* in_sizes, int n_in,
                              void* d_out, int out_size, void* d_ws, size_t ws_size,
                              hipStream_t stream)
{
    (void)in_sizes; (void)n_in; (void)d_ws; (void)ws_size; (void)out_size;
    const float* chars = (const float*)d_in[0];
    const float* W_ih  = (const float*)d_in[1];
    const float* W_hh  = (const float*)d_in[2];
    const float* b_ih  = (const float*)d_in[3];
    const float* b_hh  = (const float*)d_in[4];
    float* out = (float*)d_out;

    dim3 grid(N_ROWS / TILE_N);   // 500 blocks
    dim3 block(NTHREADS);         // 512 threads = 8 waves
    gru_fused<<<grid, block, 0, stream>>>(chars, W_ih, W_hh, b_ih, b_hh, out);
}

// Round 2
// 837.972 us; speedup vs baseline: 2.3511x; 2.3511x over previous
//
#include <hip/hip_runtime.h>
#include <cstdint>
#include <cstddef>

// Fused GRU, MFMA split-bf16 version.
// chars [16][60][2000][64] f32, W_ih/W_hh [192][64] f32, b_* [192] f32.
// out [16][2000][64] f32.
//
// Block = 64 rows (n), 512 threads = 8 waves. Wave w: jw=w>>1 (channel group,
// 16 ch), nw=w&1 (row group, 32 n). All 4 gates for a (ch,n) patch are in ONE
// wave -> epilogue is wave-local; h state (fp32) stays in VGPRs.
// x_t / h_t live in LDS as bf16 hi/lo planes [64 n][128 k] (k<64 = x, k>=64 = h),
// XOR-swizzled in 16B chunks so all DS ops sit at the b128 bank floor.
// Weights: hi/lo bf16 A-fragments in VGPRs (loaded once).
// Split product: Wh*Bh + Wh*Bl + Wl*Bh  (error ~2^-18 rel, fp32-equivalent).

typedef __bf16 bf16x8 __attribute__((ext_vector_type(8)));
typedef float  f32x4  __attribute__((ext_vector_type(4)));
typedef unsigned short u16;

union FragU { bf16x8 v; u16 u[8]; uint4 q; };

namespace {

constexpr int T_STEPS = 60;
constexpr int S_DIM   = 2000;
constexpr int N_ROWS  = 32000;
constexpr int TILE_N  = 64;
constexpr int NTH     = 512;
constexpr int PLANE   = 64 * 128;   // ushorts per plane (hi at 0, lo at +PLANE)

// swizzled ushort index into a [64 n][128 k] plane; 16B chunk = 8 ushorts,
// chunk' = chunk ^ (n&7). Keeps x (k<64) and h (k>=64) regions disjoint.
__device__ __forceinline__ int swz(int n, int k) {
    const int c = k >> 3, o = k & 7;
    return n * 128 + (((c ^ (n & 7)) << 3) | o);
}

__device__ __forceinline__ u16 bf16_rn(float f) {
    uint32_t u = __builtin_bit_cast(uint32_t, f);
    return (u16)((u + 0x7FFFu + ((u >> 16) & 1u)) >> 16);   // RTN-even
}
__device__ __forceinline__ void split2(float f, u16& hi, u16& lo) {
    const u16 h = bf16_rn(f);
    const float fh = __builtin_bit_cast(float, (uint32_t)h << 16);
    hi = h;
    lo = bf16_rn(f - fh);   // f - fh is exact in fp32
}

__global__ __launch_bounds__(NTH, 2)
void gru_mfma(const float* __restrict__ chars,
              const float* __restrict__ W_ih,
              const float* __restrict__ W_hh,
              const float* __restrict__ b_ih,
              const float* __restrict__ b_hh,
              float* __restrict__ out)
{
    __shared__ u16 SH[2 * PLANE];    // 32 KiB: hi plane, lo plane

    const int tid = threadIdx.x;
    const int l   = tid & 63;
    const int w   = tid >> 6;
    const int jw  = w >> 1;          // 0..3 -> channels [16jw, 16jw+16)
    const int nw  = w & 1;           // 0..1 -> rows [32nw, 32nw+32)
    const int ch0 = jw * 16;
    const int nb  = nw * 32;
    const int lr  = l & 15;          // lane row/col within frag
    const int lk  = l >> 4;          // lane k-group (0..3)
    const int n0  = blockIdx.x * TILE_N;

    // ---- zero the h region (k in [64,128)) of both planes ----
    {
        const int idx = (tid >> 3) * 128 + 64 + (tid & 7) * 8;  // 8 ushorts
        *(uint4*)&SH[idx]         = make_uint4(0, 0, 0, 0);
        *(uint4*)&SH[PLANE + idx] = make_uint4(0, 0, 0, 0);
    }

    // ---- A fragments (weights), hi/lo, in VGPRs. slot: 0=r, 1=z, 2=in/hn ----
    // A-frag layout (16x16x32): lane holds A[ch0 + (l&15)][32kf + (l>>4)*8 + j].
    bf16x8 WH[3][4], WL[3][4];
    {
        const int ch = ch0 + lr;
        #pragma unroll
        for (int kf = 0; kf < 4; ++kf) {
            const int k8 = kf * 32 + lk * 8;
            const float* src = (kf < 2) ? W_ih : W_hh;          // x-part vs h-part
            const int kk = (kf < 2) ? k8 : (k8 - 64);
            #pragma unroll
            for (int g = 0; g < 3; ++g) {   // rows: r=ch, z=64+ch, n-gate=128+ch
                const float* rowp = src + (size_t)(g * 64 + ch) * 64 + kk;
                const float4 f0 = *(const float4*)(rowp);
                const float4 f1 = *(const float4*)(rowp + 4);
                const float fv[8] = {f0.x, f0.y, f0.z, f0.w, f1.x, f1.y, f1.z, f1.w};
                FragU h, lo;
                #pragma unroll
                for (int j = 0; j < 8; ++j) split2(fv[j], h.u[j], lo.u[j]);
                WH[g][kf] = h.v;
                WL[g][kf] = lo.v;
            }
        }
    }

    // ---- biases (C-frag row = ch0 + lk*4 + i) ----
    float bR[4], bZ[4], bI[4], bHh[4];
    #pragma unroll
    for (int i = 0; i < 4; ++i) {
        const int ch = ch0 + lk * 4 + i;
        bR[i]  = b_ih[ch]       + b_hh[ch];
        bZ[i]  = b_ih[64 + ch]  + b_hh[64 + ch];
        bI[i]  = b_ih[128 + ch];
        bHh[i] = b_hh[128 + ch];
    }

    // ---- x staging role: thread owns row sn, cols [sk, sk+8) ----
    const int sn = tid >> 3;
    const int sk = (tid & 7) * 8;
    const int ng = n0 + sn;
    const int bb = ng / S_DIM, ss = ng % S_DIM;
    const float* xbase = chars + ((size_t)bb * T_STEPS * S_DIM + ss) * 64 + sk;
    const size_t tstr  = (size_t)S_DIM * 64;
    const int xw_off   = swz(sn, sk);

    // ---- DS addresses (t-invariant) ----
    int boff[4][2];
    #pragma unroll
    for (int kf = 0; kf < 4; ++kf)
        #pragma unroll
        for (int nf = 0; nf < 2; ++nf)
            boff[kf][nf] = swz(nb + nf * 16 + lr, kf * 32 + lk * 8);
    int hoff[2];
    #pragma unroll
    for (int nf = 0; nf < 2; ++nf)
        hoff[nf] = swz(nb + nf * 16 + lr, 64 + ch0 + lk * 4);

    // ---- stage x_0 (x region disjoint from zeroed h region: no barrier yet) ----
    {
        const float4 f0 = *(const float4*)(xbase);
        const float4 f1 = *(const float4*)(xbase + 4);
        const float fv[8] = {f0.x, f0.y, f0.z, f0.w, f1.x, f1.y, f1.z, f1.w};
        FragU h, lo;
        #pragma unroll
        for (int j = 0; j < 8; ++j) split2(fv[j], h.u[j], lo.u[j]);
        *(uint4*)&SH[xw_off]         = h.q;
        *(uint4*)&SH[PLANE + xw_off] = lo.q;
    }
    __syncthreads();

    // prefetch x_1
    float4 pf0 = *(const float4*)(xbase + tstr);
    float4 pf1 = *(const float4*)(xbase + tstr + 4);

    float ho[2][4];
    #pragma unroll
    for (int nf = 0; nf < 2; ++nf)
        #pragma unroll
        for (int i = 0; i < 4; ++i) ho[nf][i] = 0.0f;

    for (int t = 0; t < T_STEPS; ++t) {
        // ---- MFMA phase: gates = W' * [x_t; h_t] ----
        f32x4 accR[2], accZ[2], accI[2], accH[2];
        #pragma unroll
        for (int nf = 0; nf < 2; ++nf) {
            accR[nf] = f32x4{bR[0], bR[1], bR[2], bR[3]};
            accZ[nf] = f32x4{bZ[0], bZ[1], bZ[2], bZ[3]};
            accI[nf] = f32x4{bI[0], bI[1], bI[2], bI[3]};
            accH[nf] = f32x4{bHh[0], bHh[1], bHh[2], bHh[3]};
        }
        #pragma unroll
        for (int nf = 0; nf < 2; ++nf) {
            #pragma unroll
            for (int kf = 0; kf < 4; ++kf) {
                FragU bh, bl;
                bh.q = *(const uint4*)&SH[boff[kf][nf]];
                bl.q = *(const uint4*)&SH[PLANE + boff[kf][nf]];
                f32x4& g3 = (kf < 2) ? accI[nf] : accH[nf];
                accR[nf] = __builtin_amdgcn_mfma_f32_16x16x32_bf16(WH[0][kf], bh.v, accR[nf], 0, 0, 0);
                accZ[nf] = __builtin_amdgcn_mfma_f32_16x16x32_bf16(WH[1][kf], bh.v, accZ[nf], 0, 0, 0);
                g3       = __builtin_amdgcn_mfma_f32_16x16x32_bf16(WH[2][kf], bh.v, g3,       0, 0, 0);
                accR[nf] = __builtin_amdgcn_mfma_f32_16x16x32_bf16(WH[0][kf], bl.v, accR[nf], 0, 0, 0);
                accZ[nf] = __builtin_amdgcn_mfma_f32_16x16x32_bf16(WH[1][kf], bl.v, accZ[nf], 0, 0, 0);
                g3       = __builtin_amdgcn_mfma_f32_16x16x32_bf16(WH[2][kf], bl.v, g3,       0, 0, 0);
                accR[nf] = __builtin_amdgcn_mfma_f32_16x16x32_bf16(WL[0][kf], bh.v, accR[nf], 0, 0, 0);
                accZ[nf] = __builtin_amdgcn_mfma_f32_16x16x32_bf16(WL[1][kf], bh.v, accZ[nf], 0, 0, 0);
                g3       = __builtin_amdgcn_mfma_f32_16x16x32_bf16(WL[2][kf], bh.v, g3,       0, 0, 0);
            }
        }

        // ---- epilogue: wave-local gate math; h state stays in VGPRs ----
        #pragma unroll
        for (int nf = 0; nf < 2; ++nf) {
            #pragma unroll
            for (int i = 0; i < 4; ++i) {
                const float r   = __fdividef(1.0f, 1.0f + __expf(-accR[nf][i]));
                const float z   = __fdividef(1.0f, 1.0f + __expf(-accZ[nf][i]));
                const float pre = fmaf(r, accH[nf][i], accI[nf][i]);
                const float e   = __expf(-2.0f * pre);
                const float nn  = __fdividef(1.0f - e, 1.0f + e);   // tanh(pre)
                ho[nf][i] = fmaf(z, ho[nf][i] - nn, nn);            // (1-z)n + z h
            }
        }

        if (t == T_STEPS - 1) break;

        // ---- convert prefetched x_{t+1} (vmcnt wait lands here, hidden) ----
        FragU xh_, xl_;
        {
            const float fv[8] = {pf0.x, pf0.y, pf0.z, pf0.w, pf1.x, pf1.y, pf1.z, pf1.w};
            #pragma unroll
            for (int j = 0; j < 8; ++j) split2(fv[j], xh_.u[j], xl_.u[j]);
        }

        __syncthreads();   // all reads of x_t / h_t done

        // publish x_{t+1}
        *(uint4*)&SH[xw_off]         = xh_.q;
        *(uint4*)&SH[PLANE + xw_off] = xl_.q;
        // publish h_{t+1} (4 consecutive channels -> one 8B write per plane)
        #pragma unroll
        for (int nf = 0; nf < 2; ++nf) {
            u16 hh[4], hl[4];
            #pragma unroll
            for (int i = 0; i < 4; ++i) split2(ho[nf][i], hh[i], hl[i]);
            const uint2 wh = make_uint2((uint32_t)hh[0] | ((uint32_t)hh[1] << 16),
                                        (uint32_t)hh[2] | ((uint32_t)hh[3] << 16));
            const uint2 wl = make_uint2((uint32_t)hl[0] | ((uint32_t)hl[1] << 16),
                                        (uint32_t)hl[2] | ((uint32_t)hl[3] << 16));
            *(uint2*)&SH[hoff[nf]]         = wh;
            *(uint2*)&SH[PLANE + hoff[nf]] = wl;
        }

        __syncthreads();   // writes visible before next MFMA phase

        // issue x_{t+2} loads (waited-on deep into iteration t+1 -> hidden)
        if (t + 2 < T_STEPS) {
            pf0 = *(const float4*)(xbase + (size_t)(t + 2) * tstr);
            pf1 = *(const float4*)(xbase + (size_t)(t + 2) * tstr + 4);
        }
    }

    // ---- write h_final: per lane, 4 consecutive channels -> float4 ----
    #pragma unroll
    for (int nf = 0; nf < 2; ++nf) {
        const int n = n0 + nb + nf * 16 + lr;
        *(float4*)(out + (size_t)n * 64 + ch0 + lk * 4) =
            make_float4(ho[nf][0], ho[nf][1], ho[nf][2], ho[nf][3]);
    }
}

} // namespace

extern "C" void kernel_launch(void* const* d_in, const int* in_sizes, int n_in,
                              void* d_out, int out_size, void* d_ws, size_t ws_size,
                              hipStream_t stream)
{
    (void)in_sizes; (void)n_in; (void)d_ws; (void)ws_size; (void)out_size;
    const float* chars = (const float*)d_in[0];
    const float* W_ih  = (const float*)d_in[1];
    const float* W_hh  = (const float*)d_in[2];
    const float* b_ih  = (const float*)d_in[3];
    const float* b_hh  = (const float*)d_in[4];
    float* out = (float*)d_out;

    dim3 grid(N_ROWS / TILE_N);   // 500 blocks
    dim3 block(NTH);              // 512 threads = 8 waves
    gru_mfma<<<grid, block, 0, stream>>>(chars, W_ih, W_hh, b_ih, b_hh, out);
}